// Round 8
// baseline (598.920 us; speedup 1.0000x reference)
//
#include <hip/hip_runtime.h>
#include <hip/hip_fp16.h>
#include <math.h>

// ---------------------------------------------------------------------------
// TensorFieldNetwork on MI355X — round 7 design (2nd submit; round 7 bench
// never ran: GPU acquisition timeout).
// Round-6 PMC: pairF 120us, VALUBusy 75%, occ 49% (6 blocks/CU), VGPR 24.
// This round: (1) per-layer packed tables: one 32B record {v01,d01,v23,d23|
// v4,d4} per (m,f) -> b128+b64 loads instead of 5 scattered dwords;
// (2) fp16 packed lerp via __hfma2 (3 pk ops for 5 filters);
// (3) 4 splits/atom -> grid 3072 = 12 blocks/CU vs 8-resident cap (was 6).
// Fallback to 2 splits when ws_size < 24MB.
// ---------------------------------------------------------------------------

constexpr int   N_    = 768;
constexpr int   C_    = 128;
constexpr int   M_    = 512;
constexpr float DMAX_ = 6.4f;
constexpr float GAMMA_ = 1.6f;     // RBF / (HIGH - LOW)

__device__ inline unsigned pk2(float a, float b) {
    __half2 h = __floats2half2_rn(a, b);
    return *(unsigned*)&h;
}

// ---------------------------------------------------------------------------
// Kernel A: build packed radial tables.
// tab0: [m][f] 8B  {v01, d01}                       (filters 0,1   -> layer 0)
// tab1: [m][f] 32B {v01,d01,v23,d23 | v4,d4,pad}    (filters 2..6  -> layer 1)
// tab2: [m][f] 32B {v01,d01,v23,d23 | v4,d4,pad}    (filters 7..11 -> layer 2)
// fh=0 computes filters {0,1,7,8,9,10}; fh=1 {2,3,4,5,6,11} so every packed
// half2 pair lives in one thread.
// ---------------------------------------------------------------------------
__global__ __launch_bounds__(256) void build_table_kernel(
    const float* __restrict__ Rw1, const float* __restrict__ Rb1,
    const float* __restrict__ Rw2, const float* __restrict__ Rb2,
    uint2* __restrict__ tab0, char* __restrict__ tab1, char* __restrict__ tab2,
    float delta)
{
    const int f  = threadIdx.x & 127, fh = threadIdx.x >> 7;
    const int m0 = blockIdx.x * 4;

    __shared__ float hs[2][5][C_];

    const int filt0[6] = {0, 1, 7, 8, 9, 10};
    const int filt1[6] = {2, 3, 4, 5, 6, 11};

    float rbf[5][4];
    const float cent[4] = {0.0f, 2.5f / 3.0f, 5.0f / 3.0f, 2.5f};
#pragma unroll
    for (int mm = 0; mm < 5; ++mm) {
        int m = m0 + mm; if (m > M_ - 1) m = M_ - 1;
        const float d = (float)m * delta;
#pragma unroll
        for (int k = 0; k < 4; ++k) {
            const float t = d - cent[k];
            rbf[mm][k] = expf(-GAMMA_ * t * t);
        }
    }

    float outF[6][5];

    for (int ii = 0; ii < 6; ++ii) {
        const int i = fh ? filt1[ii] : filt0[ii];
        float w1v[4];
#pragma unroll
        for (int k = 0; k < 4; ++k) w1v[k] = Rw1[(i * 4 + k) * C_ + f];
        const float b1v = Rb1[i * C_ + f];

        __syncthreads();               // previous iteration's readers done
#pragma unroll
        for (int mm = 0; mm < 5; ++mm) {
            float acc = b1v;
#pragma unroll
            for (int k = 0; k < 4; ++k) acc = fmaf(rbf[mm][k], w1v[k], acc);
            hs[fh][mm][f] = fmaxf(acc, 0.0f);
        }
        __syncthreads();

        const float b2v = Rb2[i * C_ + f];
        float out[5] = {b2v, b2v, b2v, b2v, b2v};
        for (int c = 0; c < C_; ++c) {
            const float w = Rw2[(i * C_ + c) * C_ + f];
#pragma unroll
            for (int mm = 0; mm < 5; ++mm) out[mm] = fmaf(hs[fh][mm][c], w, out[mm]);
        }
#pragma unroll
        for (int mm = 0; mm < 5; ++mm) outF[ii][mm] = out[mm];
    }

#pragma unroll
    for (int mm = 0; mm < 4; ++mm) {
        const int m = m0 + mm;
        if (m >= M_) continue;
        float v[6], dl[6];
#pragma unroll
        for (int ii = 0; ii < 6; ++ii) {
            v[ii]  = outF[ii][mm];
            dl[ii] = outF[ii][mm + 1] - outF[ii][mm];
        }
        const size_t eo = (size_t)m * C_ + f;
        if (fh == 0) {
            tab0[eo] = make_uint2(pk2(v[0], v[1]), pk2(dl[0], dl[1]));
            uint4 w;                           // filters 7,8,9,10 -> tab2 slots 0-3
            w.x = pk2(v[2], v[3]); w.y = pk2(dl[2], dl[3]);
            w.z = pk2(v[4], v[5]); w.w = pk2(dl[4], dl[5]);
            *(uint4*)(tab2 + eo * 32) = w;
        } else {
            uint4 w;                           // filters 2,3,4,5 -> tab1 slots 0-3
            w.x = pk2(v[0], v[1]); w.y = pk2(dl[0], dl[1]);
            w.z = pk2(v[2], v[3]); w.w = pk2(dl[2], dl[3]);
            *(uint4*)(tab1 + eo * 32) = w;
            *(uint2*)(tab1 + eo * 32 + 16) = make_uint2(pk2(v[4], 0.f), pk2(dl[4], 0.f)); // filter 6
            *(uint2*)(tab2 + eo * 32 + 16) = make_uint2(pk2(v[5], 0.f), pk2(dl[5], 0.f)); // filter 11
        }
    }
}

// ---------------------------------------------------------------------------
// Kernel B: embedding  e[b,f] = one_hot[b,:] @ embed_W[f,:] + embed_b[f]
// ---------------------------------------------------------------------------
__global__ __launch_bounds__(256) void embed_kernel(
    const float* __restrict__ onehot, const float* __restrict__ eW,
    const float* __restrict__ eb, float* __restrict__ e)
{
    const int idx = blockIdx.x * 256 + threadIdx.x;
    const int b = idx >> 7, f = idx & 127;
    float acc = eb[f];
#pragma unroll
    for (int t = 0; t < 8; ++t) acc = fmaf(onehot[b * 8 + t], eW[f * 8 + t], acc);
    e[idx] = acc;
}

// ---------------------------------------------------------------------------
// Pair setup: {u, fr} + table byte offset for this block's neighbor range.
// ---------------------------------------------------------------------------
__device__ inline void pair_setup(const float* __restrict__ r, int a, int bbase,
                                  int nb, int tid, int qstride,
                                  float4* pair, int* qoff)
{
    const float rax = r[a * 3 + 0], ray = r[a * 3 + 1], raz = r[a * 3 + 2];
    for (int i = tid; i < nb; i += 256) {
        const int b = bbase + i;
        const float dx = rax - r[b * 3 + 0];
        const float dy = ray - r[b * 3 + 1];
        const float dz = raz - r[b * 3 + 2];
        const float d2 = fmaf(dx, dx, fmaf(dy, dy, dz * dz));
        const float d  = sqrtf(fmaxf(d2, 1e-12f));
        const float inv = 1.0f / (d + 1e-8f);
        const float t = d * ((float)(M_ - 1) / DMAX_);
        int q = (int)t; q = q > M_ - 2 ? M_ - 2 : q;
        const float fr = fminf(t - (float)q, 1.0f);
        pair[i] = make_float4(dx * inv, dy * inv, dz * inv, fr);
        qoff[i] = q * qstride;
    }
}

// ---------------------------------------------------------------------------
// Kernel C1: layer-0 pair phase. grid = nsplit*N x 256 thr.
// ---------------------------------------------------------------------------
__global__ __launch_bounds__(256, 8) void pair0_kernel(
    const float* __restrict__ r, const float* __restrict__ e,
    const uint2* __restrict__ tab0, float* __restrict__ P, int nsplit)
{
    const int a = blockIdx.x / nsplit, p = blockIdx.x - a * nsplit;
    const int tid = threadIdx.x;
    const int f = tid & 127, part = tid >> 7;
    const int nb = N_ / nsplit, bbase = p * nb;

    __shared__ float4 pair[384];
    __shared__ int    qoff[384];
    __shared__ float  sred[4][2][C_];

    pair_setup(r, a, bbase, nb, tid, C_ * 8, pair, qoff);
    __syncthreads();

    float c00 = 0.f, cx = 0.f, cy = 0.f, cz = 0.f;
    const char*  tb = (const char*)tab0 + f * 8;
    const float* ef = e + (size_t)bbase * C_ + f;
    const int half_nb = nb >> 1;
    const int iBeg = part * half_nb, iEnd = iBeg + half_nb;
    for (int i = iBeg; i < iEnd; ++i) {
        const float4 pr = pair[i];
        const uint2 W = *(const uint2*)(tb + qoff[i]);
        const float eb_ = ef[(size_t)i * C_];
        const __half2 fr2 = __float2half2_rn(pr.w);
        const __half2 t01 = __hfma2(fr2, *(const __half2*)&W.y, *(const __half2*)&W.x);
        const float t0 = __low2float(t01), t1 = __high2float(t01);
        c00 = fmaf(t0, eb_, c00);
        const float te = t1 * eb_;
        cx = fmaf(te, pr.x, cx); cy = fmaf(te, pr.y, cy); cz = fmaf(te, pr.z, cz);
    }

    sred[0][part][f] = c00;
    sred[1][part][f] = cx;
    sred[2][part][f] = cy;
    sred[3][part][f] = cz;
    __syncthreads();

    for (int idx = tid; idx < 4 * C_; idx += 256) {
        const int k = idx >> 7, c = idx & 127;
        P[((size_t)(p * N_ + a) * 4) * C_ + idx] = sred[k][0][c] + sred[k][1][c];
    }
}

// ---------------------------------------------------------------------------
// Kernel C2: full-layer pair phase. grid = nsplit*N x 256 thr.
// tab = tab1 (layer 1) or tab2 (layer 2); 32B records.
// ---------------------------------------------------------------------------
__global__ __launch_bounds__(256, 8) void pairF_kernel(
    const float* __restrict__ r, const uint2* __restrict__ xin,
    const char* __restrict__ tab, float* __restrict__ P, int nsplit)
{
    const int a = blockIdx.x / nsplit, p = blockIdx.x - a * nsplit;
    const int tid = threadIdx.x;
    const int f = tid & 127, part = tid >> 7;
    const int nb = N_ / nsplit, bbase = p * nb;

    __shared__ float4 pair[384];
    __shared__ int    qoff[384];
    __shared__ float  sred[11][2][C_];

    pair_setup(r, a, bbase, nb, tid, C_ * 32, pair, qoff);
    __syncthreads();

    float a0 = 0.f, b1x = 0.f, b1y = 0.f, b1z = 0.f;
    float a1x = 0.f, a1y = 0.f, a1z = 0.f;
    float o0 = 0.f, o1x = 0.f, o1y = 0.f, o1z = 0.f;

    const char*  tb = tab + f * 32;
    const uint2* xf = xin + (size_t)bbase * C_ + f;
    const int half_nb = nb >> 1;
    const int iBeg = part * half_nb, iEnd = iBeg + half_nb;
    for (int i = iBeg; i < iEnd; ++i) {
        const float4 pr = pair[i];
        const int off = qoff[i];
        const uint4 Wa = *(const uint4*)(tb + off);
        const uint2 Wb = *(const uint2*)(tb + off + 16);
        const uint2 xw = xf[(size_t)i * C_];

        const __half2 fr2 = __float2half2_rn(pr.w);
        const __half2 t01 = __hfma2(fr2, *(const __half2*)&Wa.y, *(const __half2*)&Wa.x);
        const __half2 t23 = __hfma2(fr2, *(const __half2*)&Wa.w, *(const __half2*)&Wa.z);
        const __half2 t4h = __hfma2(fr2, *(const __half2*)&Wb.y, *(const __half2*)&Wb.x);
        const float t0 = __low2float(t01), t1 = __high2float(t01);
        const float t2 = __low2float(t23), t3 = __high2float(t23);
        const float t4 = __low2float(t4h);

        const float2 x01 = __half22float2(*(const __half2*)&xw.x);
        const float2 x23 = __half22float2(*(const __half2*)&xw.y);
        const float x0b = x01.x, xbx = x01.y, xby = x23.x, xbz = x23.y;

        a0 = fmaf(t0, x0b, a0);
        const float tb_ = t1 * x0b;
        b1x = fmaf(tb_, pr.x, b1x); b1y = fmaf(tb_, pr.y, b1y); b1z = fmaf(tb_, pr.z, b1z);
        a1x = fmaf(t2, xbx, a1x); a1y = fmaf(t2, xby, a1y); a1z = fmaf(t2, xbz, a1z);
        const float ud = fmaf(pr.x, xbx, fmaf(pr.y, xby, pr.z * xbz));
        o0 = fmaf(t3, ud, o0);
        const float crx = pr.y * xbz - pr.z * xby;
        const float cry = pr.z * xbx - pr.x * xbz;
        const float crz = pr.x * xby - pr.y * xbx;
        o1x = fmaf(t4, crx, o1x); o1y = fmaf(t4, cry, o1y); o1z = fmaf(t4, crz, o1z);
    }

    sred[0][part][f] = a0;
    sred[1][part][f] = b1x; sred[2][part][f] = b1y; sred[3][part][f] = b1z;
    sred[4][part][f] = a1x; sred[5][part][f] = a1y; sred[6][part][f] = a1z;
    sred[7][part][f] = o0;
    sred[8][part][f] = o1x; sred[9][part][f] = o1y; sred[10][part][f] = o1z;
    __syncthreads();

    for (int idx = tid; idx < 11 * C_; idx += 256) {
        const int k = idx >> 7, c = idx & 127;
        P[((size_t)(p * N_ + a) * 11) * C_ + idx] = sred[k][0][c] + sred[k][1][c];
    }
}

// ---------------------------------------------------------------------------
// Kernel D1: layer-0 finish.
// ---------------------------------------------------------------------------
__global__ __launch_bounds__(512) void finish0_kernel(
    const float* __restrict__ P,
    const float* __restrict__ w0, const float* __restrict__ b0v,
    const float* __restrict__ w1, const float* __restrict__ nlb,
    uint2* __restrict__ xout, int nsplit)
{
    const int a = blockIdx.x, tid = threadIdx.x;
    const int f = tid & 127;

    __shared__ float s[4 * C_];
    __shared__ float ys[4 * C_];

    for (int idx = tid; idx < 4 * C_; idx += 512) {
        float acc = 0.f;
        for (int sp = 0; sp < nsplit; ++sp)
            acc += P[((size_t)(sp * N_ + a) * 4) * C_ + idx];
        s[idx] = acc;
    }
    __syncthreads();

    {
        const int j = tid >> 7;
        float y;
        if (j == 0) {
            y = b0v[f];
            const float4* w = (const float4*)(w0 + (size_t)f * C_);
            for (int c4 = 0; c4 < C_ / 4; ++c4) {
                const float4 wv = w[c4];
                y = fmaf(wv.x, s[c4 * 4 + 0], y);
                y = fmaf(wv.y, s[c4 * 4 + 1], y);
                y = fmaf(wv.z, s[c4 * 4 + 2], y);
                y = fmaf(wv.w, s[c4 * 4 + 3], y);
            }
        } else {
            y = 0.f;
            const float4* w = (const float4*)(w1 + (size_t)f * C_);
            const float* sj = s + j * C_;
            for (int c4 = 0; c4 < C_ / 4; ++c4) {
                const float4 wv = w[c4];
                y = fmaf(wv.x, sj[c4 * 4 + 0], y);
                y = fmaf(wv.y, sj[c4 * 4 + 1], y);
                y = fmaf(wv.z, sj[c4 * 4 + 2], y);
                y = fmaf(wv.w, sj[c4 * 4 + 3], y);
            }
        }
        ys[j * C_ + f] = y;
    }
    __syncthreads();

    if (tid < C_) {
        const float y0 = ys[tid];
        const float yx = ys[C_ + tid], yy = ys[2 * C_ + tid], yz = ys[3 * C_ + tid];
        const float x0v = y0 > 0.f ? y0 : expm1f(y0);
        const float nsq = fmaf(yx, yx, fmaf(yy, yy, yz * yz));
        const float nn  = sqrtf(fmaxf(nsq, 1e-12f));
        const float g   = nlb[tid] + nn;
        const float sc  = (g > 0.f ? g : expm1f(g)) / nn;
        uint2 w;
        *(__half2*)&w.x = __floats2half2_rn(x0v, yx * sc);
        *(__half2*)&w.y = __floats2half2_rn(yy * sc, yz * sc);
        xout[(size_t)a * C_ + tid] = w;
    }
}

// ---------------------------------------------------------------------------
// Kernel D2: full-layer finish.
// ---------------------------------------------------------------------------
template <bool NONLIN, bool LAST>
__global__ __launch_bounds__(512) void finishF_kernel(
    const float* __restrict__ P,
    const float* __restrict__ w0, const float* __restrict__ b0v,
    const float* __restrict__ w1, const float* __restrict__ nlb,
    uint2* __restrict__ xout,
    float* __restrict__ out, const float* __restrict__ predW,
    const float* __restrict__ predb, int nsplit)
{
    const int a = blockIdx.x, tid = threadIdx.x;
    const int f = tid & 127;

    __shared__ float s[11 * C_];
    __shared__ float ys[4 * C_];

    for (int idx = tid; idx < 11 * C_; idx += 512) {
        float acc = 0.f;
        for (int sp = 0; sp < nsplit; ++sp)
            acc += P[((size_t)(sp * N_ + a) * 11) * C_ + idx];
        s[idx] = acc;
    }
    __syncthreads();

    {
        const int j = tid >> 7;
        float y;
        if (j == 0) {
            y = b0v[f];
            const float4* w = (const float4*)(w0 + (size_t)f * (2 * C_));
            const float* s0 = s + 0 * C_;
            const float* s7 = s + 7 * C_;
            for (int c4 = 0; c4 < C_ / 4; ++c4) {
                const float4 wa = w[c4];
                const float4 wb = w[C_ / 4 + c4];
                y = fmaf(wa.x, s0[c4 * 4 + 0], y);
                y = fmaf(wa.y, s0[c4 * 4 + 1], y);
                y = fmaf(wa.z, s0[c4 * 4 + 2], y);
                y = fmaf(wa.w, s0[c4 * 4 + 3], y);
                y = fmaf(wb.x, s7[c4 * 4 + 0], y);
                y = fmaf(wb.y, s7[c4 * 4 + 1], y);
                y = fmaf(wb.z, s7[c4 * 4 + 2], y);
                y = fmaf(wb.w, s7[c4 * 4 + 3], y);
            }
        } else {
            y = 0.f;
            const float4* w = (const float4*)(w1 + (size_t)f * (3 * C_));
            const float* sb = s + j * C_;
            const float* sa = s + (3 + j) * C_;
            const float* so = s + (7 + j) * C_;
            for (int c4 = 0; c4 < C_ / 4; ++c4) {
                const float4 w_b = w[c4];
                const float4 w_a = w[C_ / 4 + c4];
                const float4 w_o = w[2 * (C_ / 4) + c4];
                y = fmaf(w_b.x, sb[c4 * 4 + 0], y);
                y = fmaf(w_b.y, sb[c4 * 4 + 1], y);
                y = fmaf(w_b.z, sb[c4 * 4 + 2], y);
                y = fmaf(w_b.w, sb[c4 * 4 + 3], y);
                y = fmaf(w_a.x, sa[c4 * 4 + 0], y);
                y = fmaf(w_a.y, sa[c4 * 4 + 1], y);
                y = fmaf(w_a.z, sa[c4 * 4 + 2], y);
                y = fmaf(w_a.w, sa[c4 * 4 + 3], y);
                y = fmaf(w_o.x, so[c4 * 4 + 0], y);
                y = fmaf(w_o.y, so[c4 * 4 + 1], y);
                y = fmaf(w_o.z, so[c4 * 4 + 2], y);
                y = fmaf(w_o.w, so[c4 * 4 + 3], y);
            }
        }
        ys[j * C_ + f] = y;
    }
    __syncthreads();

    if (NONLIN) {
        if (tid < C_) {
            const float y0 = ys[tid];
            const float yx = ys[C_ + tid], yy = ys[2 * C_ + tid], yz = ys[3 * C_ + tid];
            const float x0v = y0 > 0.f ? y0 : expm1f(y0);
            const float nsq = fmaf(yx, yx, fmaf(yy, yy, yz * yz));
            const float nn  = sqrtf(fmaxf(nsq, 1e-12f));
            const float g   = nlb[tid] + nn;
            const float sc  = (g > 0.f ? g : expm1f(g)) / nn;
            uint2 w;
            *(__half2*)&w.x = __floats2half2_rn(x0v, yx * sc);
            *(__half2*)&w.y = __floats2half2_rn(yy * sc, yz * sc);
            xout[(size_t)a * C_ + tid] = w;
        }
    }
    if (LAST) {
        if (tid < C_) {
            const float y0 = ys[tid];
            const float yx = ys[C_ + tid], yy = ys[2 * C_ + tid], yz = ys[3 * C_ + tid];
            out[a * C_ + tid] = y0;                   // x0 [N,C,1]
            float* o1 = out + N_ * C_;                // x1 [N,C,3]
            o1[a * (C_ * 3) + tid * 3 + 0] = yx;
            o1[a * (C_ * 3) + tid * 3 + 1] = yy;
            o1[a * (C_ * 3) + tid * 3 + 2] = yz;
        }
        __syncthreads();
        if (tid < 8) {                                // atom head from ys[0..127]
            float acc = predb[tid];
            for (int c = 0; c < C_; ++c)
                acc = fmaf(predW[tid * C_ + c], ys[c], acc);
            out[N_ * C_ + N_ * C_ * 3 + a * 8 + tid] = acc;
        }
    }
}

// ---------------------------------------------------------------------------
extern "C" void kernel_launch(void* const* d_in, const int* in_sizes, int n_in,
                              void* d_out, int out_size, void* d_ws, size_t ws_size,
                              hipStream_t stream)
{
    const float* r       = (const float*)d_in[0];
    const float* onehot  = (const float*)d_in[1];
    const float* embed_W = (const float*)d_in[2];
    const float* embed_b = (const float*)d_in[3];
    const float* Rw1     = (const float*)d_in[4];
    const float* Rb1     = (const float*)d_in[5];
    const float* Rw2     = (const float*)d_in[6];
    const float* Rb2     = (const float*)d_in[7];
    const float* si0_w0  = (const float*)d_in[8];
    const float* si0_b0  = (const float*)d_in[9];
    const float* si0_w1  = (const float*)d_in[10];
    const float* si1_w0  = (const float*)d_in[11];
    const float* si1_b0  = (const float*)d_in[12];
    const float* si1_w1  = (const float*)d_in[13];
    const float* si2_w0  = (const float*)d_in[14];
    const float* si2_b0  = (const float*)d_in[15];
    const float* si2_w1  = (const float*)d_in[16];
    const float* nl_b0   = (const float*)d_in[17];
    const float* nl_b1   = (const float*)d_in[18];
    const float* pred_W  = (const float*)d_in[19];
    const float* pred_b  = (const float*)d_in[20];
    (void)in_sizes; (void)n_in; (void)out_size;

    const float delta = DMAX_ / (float)(M_ - 1);

    // workspace (bytes):
    //   tab1: M*C*32 = 2,097,152    tab2: 2,097,152    tab0: M*C*8 = 524,288
    //   e: N*C*4 = 393,216          xa/xb: N*C*8 = 786,432 each
    //   P: nsplit*N*11*C*4          (4 -> 17.3MB, total 23.99MB; 2 -> 15.3MB)
    char* wsb = (char*)d_ws;
    size_t off = 0;
    char*  tab1 = wsb + off; off += (size_t)M_ * C_ * 32;
    char*  tab2 = wsb + off; off += (size_t)M_ * C_ * 32;
    uint2* tab0 = (uint2*)(wsb + off); off += (size_t)M_ * C_ * 8;
    float* e    = (float*)(wsb + off); off += (size_t)N_ * C_ * 4;
    uint2* xa   = (uint2*)(wsb + off); off += (size_t)N_ * C_ * 8;
    uint2* xb   = (uint2*)(wsb + off); off += (size_t)N_ * C_ * 8;
    float* P    = (float*)(wsb + off);

    const size_t p4 = 4ull * N_ * 11 * C_ * 4;
    const int nsplit = (ws_size >= off + p4) ? 4 : 2;

    float* out = (float*)d_out;

    build_table_kernel<<<M_ / 4, 256, 0, stream>>>(Rw1, Rb1, Rw2, Rb2,
                                                   tab0, tab1, tab2, delta);
    embed_kernel<<<(N_ * C_) / 256, 256, 0, stream>>>(onehot, embed_W, embed_b, e);

    // layer 0
    pair0_kernel<<<nsplit * N_, 256, 0, stream>>>(r, e, tab0, P, nsplit);
    finish0_kernel<<<N_, 512, 0, stream>>>(P, si0_w0, si0_b0, si0_w1, nl_b0,
                                           xa, nsplit);

    // layer 1
    pairF_kernel<<<nsplit * N_, 256, 0, stream>>>(r, xa, tab1, P, nsplit);
    finishF_kernel<true, false><<<N_, 512, 0, stream>>>(
        P, si1_w0, si1_b0, si1_w1, nl_b1, xb, nullptr, nullptr, nullptr, nsplit);

    // layer 2 (last)
    pairF_kernel<<<nsplit * N_, 256, 0, stream>>>(r, xb, tab2, P, nsplit);
    finishF_kernel<false, true><<<N_, 512, 0, stream>>>(
        P, si2_w0, si2_b0, si2_w1, nullptr, nullptr, out, pred_W, pred_b, nsplit);
}

// Round 9
// 496.539 us; speedup vs baseline: 1.2062x; 1.2062x over previous
//
#include <hip/hip_runtime.h>
#include <hip/hip_fp16.h>
#include <math.h>

// ---------------------------------------------------------------------------
// TensorFieldNetwork on MI355X — round 9.
// Round-8 lessons: packed 32B table records were a coalescing regression
// (FETCH 4.7->8.9MB, pairF 120->132us); VALUBusy ~71-75% independent of
// occupancy -> pair loop is instruction-bound. finishF re-reads 720KB of SI
// weights per atom -> ~550MB L2 traffic.
// This round: (a) coalesced [m][12][C] half2 {v,d} table (round-6 proven);
// (b) fma_mix-shaped lerps (no explicit half->float cvts); (c) nsplit=3,
// grid 2304 -> ~8 blocks/CU resident; (d) finish kernels process 3 atoms per
// block (3x weight-read amortization, float4 LDS reads).
// ---------------------------------------------------------------------------

constexpr int   N_     = 768;
constexpr int   C_     = 128;
constexpr int   M_     = 512;
constexpr int   NSPLIT = 3;
constexpr int   NB_    = N_ / NSPLIT;   // 256 neighbors per pair-block
constexpr int   TA_    = 3;             // atoms per finish block
constexpr float DMAX_  = 6.4f;
constexpr float GAMMA_ = 1.6f;          // RBF / (HIGH - LOW)

// lerp from packed {v, d} half2: t = v + fr * d   (fma_mix candidate)
__device__ inline float lerp_vd(float fr, __half2 vd) {
    return fmaf(fr, __half2float(__high2half(vd)), __half2float(__low2half(vd)));
}

// ---------------------------------------------------------------------------
// Kernel A: build radial tables, fp16 {val, delta}, layout tab[(m*12+i)*C+f].
// ---------------------------------------------------------------------------
__global__ __launch_bounds__(256) void build_table_kernel(
    const float* __restrict__ Rw1, const float* __restrict__ Rb1,
    const float* __restrict__ Rw2, const float* __restrict__ Rb2,
    __half2* __restrict__ tab, float delta)
{
    const int f  = threadIdx.x & 127, fh = threadIdx.x >> 7;
    const int m0 = blockIdx.x * 4;

    __shared__ float hs[2][5][C_];

    float rbf[5][4];
    const float cent[4] = {0.0f, 2.5f / 3.0f, 5.0f / 3.0f, 2.5f};
#pragma unroll
    for (int mm = 0; mm < 5; ++mm) {
        int m = m0 + mm; if (m > M_ - 1) m = M_ - 1;
        const float d = (float)m * delta;
#pragma unroll
        for (int k = 0; k < 4; ++k) {
            const float t = d - cent[k];
            rbf[mm][k] = expf(-GAMMA_ * t * t);
        }
    }

    for (int ii = 0; ii < 6; ++ii) {
        const int i = fh * 6 + ii;
        float w1v[4];
#pragma unroll
        for (int k = 0; k < 4; ++k) w1v[k] = Rw1[(i * 4 + k) * C_ + f];
        const float b1v = Rb1[i * C_ + f];

        __syncthreads();               // previous iteration's readers done
#pragma unroll
        for (int mm = 0; mm < 5; ++mm) {
            float acc = b1v;
#pragma unroll
            for (int k = 0; k < 4; ++k) acc = fmaf(rbf[mm][k], w1v[k], acc);
            hs[fh][mm][f] = fmaxf(acc, 0.0f);
        }
        __syncthreads();

        const float b2v = Rb2[i * C_ + f];
        float out[5] = {b2v, b2v, b2v, b2v, b2v};
        for (int c = 0; c < C_; ++c) {
            const float w = Rw2[(i * C_ + c) * C_ + f];
#pragma unroll
            for (int mm = 0; mm < 5; ++mm) out[mm] = fmaf(hs[fh][mm][c], w, out[mm]);
        }
#pragma unroll
        for (int mm = 0; mm < 4; ++mm) {
            const int m = m0 + mm;
            if (m < M_)
                tab[((size_t)m * 12 + i) * C_ + f] =
                    __floats2half2_rn(out[mm], out[mm + 1] - out[mm]);
        }
    }
}

// ---------------------------------------------------------------------------
// Kernel B: embedding
// ---------------------------------------------------------------------------
__global__ __launch_bounds__(256) void embed_kernel(
    const float* __restrict__ onehot, const float* __restrict__ eW,
    const float* __restrict__ eb, float* __restrict__ e)
{
    const int idx = blockIdx.x * 256 + threadIdx.x;
    const int b = idx >> 7, f = idx & 127;
    float acc = eb[f];
#pragma unroll
    for (int t = 0; t < 8; ++t) acc = fmaf(onehot[b * 8 + t], eW[f * 8 + t], acc);
    e[idx] = acc;
}

// ---------------------------------------------------------------------------
// Pair setup: {u, fr} + table element offset (q*12+RI)*C for NB_ neighbors.
// ---------------------------------------------------------------------------
__device__ inline void pair_setup(const float* __restrict__ r, int a, int bbase,
                                  int tid, int RI, float4* pair, int* qoff)
{
    const float rax = r[a * 3 + 0], ray = r[a * 3 + 1], raz = r[a * 3 + 2];
    for (int i = tid; i < NB_; i += 256) {
        const int b = bbase + i;
        const float dx = rax - r[b * 3 + 0];
        const float dy = ray - r[b * 3 + 1];
        const float dz = raz - r[b * 3 + 2];
        const float d2 = fmaf(dx, dx, fmaf(dy, dy, dz * dz));
        const float d  = sqrtf(fmaxf(d2, 1e-12f));
        const float inv = 1.0f / (d + 1e-8f);
        const float t = d * ((float)(M_ - 1) / DMAX_);
        int q = (int)t; q = q > M_ - 2 ? M_ - 2 : q;
        const float fr = fminf(t - (float)q, 1.0f);
        pair[i] = make_float4(dx * inv, dy * inv, dz * inv, fr);
        qoff[i] = (q * 12 + RI) * C_;
    }
}

// ---------------------------------------------------------------------------
// Kernel C1: layer-0 pair phase. grid = NSPLIT*N x 256 thr.
// ---------------------------------------------------------------------------
__global__ __launch_bounds__(256, 8) void pair0_kernel(
    const float* __restrict__ r, const float* __restrict__ e,
    const __half2* __restrict__ tab, float* __restrict__ P)
{
    const int a = blockIdx.x / NSPLIT, p = blockIdx.x - a * NSPLIT;
    const int tid = threadIdx.x;
    const int f = tid & 127, part = tid >> 7;
    const int bbase = p * NB_;

    __shared__ float4 pair[NB_];
    __shared__ int    qoff[NB_];
    __shared__ float  sred[4][2][C_];

    pair_setup(r, a, bbase, tid, 0, pair, qoff);
    __syncthreads();

    float c00 = 0.f, cx = 0.f, cy = 0.f, cz = 0.f;
    const __half2* tabf = tab + f;
    const float*   ef   = e + (size_t)bbase * C_ + f;
    const int iBeg = part * (NB_ / 2), iEnd = iBeg + (NB_ / 2);
    for (int i = iBeg; i < iEnd; ++i) {
        const float4 pr = pair[i];
        const __half2* tp = tabf + qoff[i];
        const __half2 h0 = tp[0], h1 = tp[C_];
        const float eb_ = ef[(size_t)i * C_];
        const float fr = pr.w;
        const float t0 = lerp_vd(fr, h0);
        const float t1 = lerp_vd(fr, h1);
        c00 = fmaf(t0, eb_, c00);
        const float te = t1 * eb_;
        cx = fmaf(te, pr.x, cx); cy = fmaf(te, pr.y, cy); cz = fmaf(te, pr.z, cz);
    }

    sred[0][part][f] = c00;
    sred[1][part][f] = cx;
    sred[2][part][f] = cy;
    sred[3][part][f] = cz;
    __syncthreads();

    for (int idx = tid; idx < 4 * C_; idx += 256) {
        const int k = idx >> 7, c = idx & 127;
        P[((size_t)(p * N_ + a) * 4) * C_ + idx] = sred[k][0][c] + sred[k][1][c];
    }
}

// ---------------------------------------------------------------------------
// Kernel C2: full-layer pair phase (RI = 2 or 7). grid = NSPLIT*N x 256 thr.
// ---------------------------------------------------------------------------
__global__ __launch_bounds__(256, 8) void pairF_kernel(
    const float* __restrict__ r, const uint2* __restrict__ xin,
    const __half2* __restrict__ tab, int RI, float* __restrict__ P)
{
    const int a = blockIdx.x / NSPLIT, p = blockIdx.x - a * NSPLIT;
    const int tid = threadIdx.x;
    const int f = tid & 127, part = tid >> 7;
    const int bbase = p * NB_;

    __shared__ float4 pair[NB_];
    __shared__ int    qoff[NB_];
    __shared__ float  sred[11][2][C_];

    pair_setup(r, a, bbase, tid, RI, pair, qoff);
    __syncthreads();

    float a0 = 0.f, b1x = 0.f, b1y = 0.f, b1z = 0.f;
    float a1x = 0.f, a1y = 0.f, a1z = 0.f;
    float o0 = 0.f, o1x = 0.f, o1y = 0.f, o1z = 0.f;

    const __half2* tabf = tab + f;
    const uint2*   xf   = xin + (size_t)bbase * C_ + f;
    const int iBeg = part * (NB_ / 2), iEnd = iBeg + (NB_ / 2);
    for (int i = iBeg; i < iEnd; ++i) {
        const float4 pr = pair[i];
        const __half2* tp = tabf + qoff[i];
        const __half2 h0 = tp[0 * C_], h1 = tp[1 * C_], h2 = tp[2 * C_];
        const __half2 h3 = tp[3 * C_], h4 = tp[4 * C_];
        const uint2 xw = xf[(size_t)i * C_];

        const float fr = pr.w;
        const float t0 = lerp_vd(fr, h0);
        const float t1 = lerp_vd(fr, h1);
        const float t2 = lerp_vd(fr, h2);
        const float t3 = lerp_vd(fr, h3);
        const float t4 = lerp_vd(fr, h4);

        const __half2 xh01 = *(const __half2*)&xw.x;
        const __half2 xh23 = *(const __half2*)&xw.y;
        const float x0b = __half2float(__low2half(xh01));
        const float xbx = __half2float(__high2half(xh01));
        const float xby = __half2float(__low2half(xh23));
        const float xbz = __half2float(__high2half(xh23));

        a0 = fmaf(t0, x0b, a0);
        const float tb = t1 * x0b;
        b1x = fmaf(tb, pr.x, b1x); b1y = fmaf(tb, pr.y, b1y); b1z = fmaf(tb, pr.z, b1z);
        a1x = fmaf(t2, xbx, a1x); a1y = fmaf(t2, xby, a1y); a1z = fmaf(t2, xbz, a1z);
        const float ud = fmaf(pr.x, xbx, fmaf(pr.y, xby, pr.z * xbz));
        o0 = fmaf(t3, ud, o0);
        const float crx = pr.y * xbz - pr.z * xby;
        const float cry = pr.z * xbx - pr.x * xbz;
        const float crz = pr.x * xby - pr.y * xbx;
        o1x = fmaf(t4, crx, o1x); o1y = fmaf(t4, cry, o1y); o1z = fmaf(t4, crz, o1z);
    }

    sred[0][part][f] = a0;
    sred[1][part][f] = b1x; sred[2][part][f] = b1y; sred[3][part][f] = b1z;
    sred[4][part][f] = a1x; sred[5][part][f] = a1y; sred[6][part][f] = a1z;
    sred[7][part][f] = o0;
    sred[8][part][f] = o1x; sred[9][part][f] = o1y; sred[10][part][f] = o1z;
    __syncthreads();

    for (int idx = tid; idx < 11 * C_; idx += 256) {
        const int k = idx >> 7, c = idx & 127;
        P[((size_t)(p * N_ + a) * 11) * C_ + idx] = sred[k][0][c] + sred[k][1][c];
    }
}

// ---------------------------------------------------------------------------
// Kernel D1: layer-0 finish. grid = N/TA x 512 thr; TA atoms per block.
// ---------------------------------------------------------------------------
__global__ __launch_bounds__(512) void finish0_kernel(
    const float* __restrict__ P,
    const float* __restrict__ w0, const float* __restrict__ b0v,
    const float* __restrict__ w1, const float* __restrict__ nlb,
    uint2* __restrict__ xout)
{
    const int a0_ = blockIdx.x * TA_, tid = threadIdx.x;
    const int f = tid & 127, j = tid >> 7;

    __shared__ float s[TA_][4 * C_];
    __shared__ float ys[TA_][4 * C_];

    for (int t = 0; t < TA_; ++t)
        for (int idx = tid; idx < 4 * C_; idx += 512) {
            float acc = 0.f;
            for (int sp = 0; sp < NSPLIT; ++sp)
                acc += P[((size_t)(sp * N_ + a0_ + t) * 4) * C_ + idx];
            s[t][idx] = acc;
        }
    __syncthreads();

    float acc[TA_];
    if (j == 0) {
        const float b0 = b0v[f];
#pragma unroll
        for (int t = 0; t < TA_; ++t) acc[t] = b0;
        const float4* w = (const float4*)(w0 + (size_t)f * C_);
        for (int c4 = 0; c4 < C_ / 4; ++c4) {
            const float4 wv = w[c4];
#pragma unroll
            for (int t = 0; t < TA_; ++t) {
                const float4 sv = *(const float4*)&s[t][c4 * 4];
                acc[t] = fmaf(wv.x, sv.x, acc[t]);
                acc[t] = fmaf(wv.y, sv.y, acc[t]);
                acc[t] = fmaf(wv.z, sv.z, acc[t]);
                acc[t] = fmaf(wv.w, sv.w, acc[t]);
            }
        }
    } else {
#pragma unroll
        for (int t = 0; t < TA_; ++t) acc[t] = 0.f;
        const float4* w = (const float4*)(w1 + (size_t)f * C_);
        for (int c4 = 0; c4 < C_ / 4; ++c4) {
            const float4 wv = w[c4];
#pragma unroll
            for (int t = 0; t < TA_; ++t) {
                const float4 sv = *(const float4*)&s[t][j * C_ + c4 * 4];
                acc[t] = fmaf(wv.x, sv.x, acc[t]);
                acc[t] = fmaf(wv.y, sv.y, acc[t]);
                acc[t] = fmaf(wv.z, sv.z, acc[t]);
                acc[t] = fmaf(wv.w, sv.w, acc[t]);
            }
        }
    }
#pragma unroll
    for (int t = 0; t < TA_; ++t) ys[t][j * C_ + f] = acc[t];
    __syncthreads();

    if (tid < TA_ * C_) {
        const int t = tid >> 7, ff = tid & 127;
        const float y0 = ys[t][ff];
        const float yx = ys[t][C_ + ff], yy = ys[t][2 * C_ + ff], yz = ys[t][3 * C_ + ff];
        const float x0v = y0 > 0.f ? y0 : expm1f(y0);
        const float nsq = fmaf(yx, yx, fmaf(yy, yy, yz * yz));
        const float nn  = sqrtf(fmaxf(nsq, 1e-12f));
        const float g   = nlb[ff] + nn;
        const float sc  = (g > 0.f ? g : expm1f(g)) / nn;
        uint2 w;
        *(__half2*)&w.x = __floats2half2_rn(x0v, yx * sc);
        *(__half2*)&w.y = __floats2half2_rn(yy * sc, yz * sc);
        xout[(size_t)(a0_ + t) * C_ + ff] = w;
    }
}

// ---------------------------------------------------------------------------
// Kernel D2: full-layer finish. grid = N/TA x 512 thr.
// ---------------------------------------------------------------------------
template <bool NONLIN, bool LAST>
__global__ __launch_bounds__(512) void finishF_kernel(
    const float* __restrict__ P,
    const float* __restrict__ w0, const float* __restrict__ b0v,
    const float* __restrict__ w1, const float* __restrict__ nlb,
    uint2* __restrict__ xout,
    float* __restrict__ out, const float* __restrict__ predW,
    const float* __restrict__ predb)
{
    const int a0_ = blockIdx.x * TA_, tid = threadIdx.x;
    const int f = tid & 127, j = tid >> 7;

    __shared__ float s[TA_][11 * C_];
    __shared__ float ys[TA_][4 * C_];

    for (int t = 0; t < TA_; ++t)
        for (int idx = tid; idx < 11 * C_; idx += 512) {
            float acc = 0.f;
            for (int sp = 0; sp < NSPLIT; ++sp)
                acc += P[((size_t)(sp * N_ + a0_ + t) * 11) * C_ + idx];
            s[t][idx] = acc;
        }
    __syncthreads();

    float acc[TA_];
    if (j == 0) {
        const float b0 = b0v[f];
#pragma unroll
        for (int t = 0; t < TA_; ++t) acc[t] = b0;
        const float4* w = (const float4*)(w0 + (size_t)f * (2 * C_));
        for (int c4 = 0; c4 < C_ / 4; ++c4) {
            const float4 wa = w[c4];
            const float4 wb = w[C_ / 4 + c4];
#pragma unroll
            for (int t = 0; t < TA_; ++t) {
                const float4 s0 = *(const float4*)&s[t][c4 * 4];
                const float4 s7 = *(const float4*)&s[t][7 * C_ + c4 * 4];
                acc[t] = fmaf(wa.x, s0.x, acc[t]);
                acc[t] = fmaf(wa.y, s0.y, acc[t]);
                acc[t] = fmaf(wa.z, s0.z, acc[t]);
                acc[t] = fmaf(wa.w, s0.w, acc[t]);
                acc[t] = fmaf(wb.x, s7.x, acc[t]);
                acc[t] = fmaf(wb.y, s7.y, acc[t]);
                acc[t] = fmaf(wb.z, s7.z, acc[t]);
                acc[t] = fmaf(wb.w, s7.w, acc[t]);
            }
        }
    } else {
#pragma unroll
        for (int t = 0; t < TA_; ++t) acc[t] = 0.f;
        const float4* w = (const float4*)(w1 + (size_t)f * (3 * C_));
        for (int c4 = 0; c4 < C_ / 4; ++c4) {
            const float4 wb = w[c4];
            const float4 wa = w[C_ / 4 + c4];
            const float4 wo = w[2 * (C_ / 4) + c4];
#pragma unroll
            for (int t = 0; t < TA_; ++t) {
                const float4 sb = *(const float4*)&s[t][j * C_ + c4 * 4];
                const float4 sa = *(const float4*)&s[t][(3 + j) * C_ + c4 * 4];
                const float4 so = *(const float4*)&s[t][(7 + j) * C_ + c4 * 4];
                acc[t] = fmaf(wb.x, sb.x, acc[t]);
                acc[t] = fmaf(wb.y, sb.y, acc[t]);
                acc[t] = fmaf(wb.z, sb.z, acc[t]);
                acc[t] = fmaf(wb.w, sb.w, acc[t]);
                acc[t] = fmaf(wa.x, sa.x, acc[t]);
                acc[t] = fmaf(wa.y, sa.y, acc[t]);
                acc[t] = fmaf(wa.z, sa.z, acc[t]);
                acc[t] = fmaf(wa.w, sa.w, acc[t]);
                acc[t] = fmaf(wo.x, so.x, acc[t]);
                acc[t] = fmaf(wo.y, so.y, acc[t]);
                acc[t] = fmaf(wo.z, so.z, acc[t]);
                acc[t] = fmaf(wo.w, so.w, acc[t]);
            }
        }
    }
#pragma unroll
    for (int t = 0; t < TA_; ++t) ys[t][j * C_ + f] = acc[t];
    __syncthreads();

    if (NONLIN) {
        if (tid < TA_ * C_) {
            const int t = tid >> 7, ff = tid & 127;
            const float y0 = ys[t][ff];
            const float yx = ys[t][C_ + ff], yy = ys[t][2 * C_ + ff], yz = ys[t][3 * C_ + ff];
            const float x0v = y0 > 0.f ? y0 : expm1f(y0);
            const float nsq = fmaf(yx, yx, fmaf(yy, yy, yz * yz));
            const float nn  = sqrtf(fmaxf(nsq, 1e-12f));
            const float g   = nlb[ff] + nn;
            const float sc  = (g > 0.f ? g : expm1f(g)) / nn;
            uint2 w;
            *(__half2*)&w.x = __floats2half2_rn(x0v, yx * sc);
            *(__half2*)&w.y = __floats2half2_rn(yy * sc, yz * sc);
            xout[(size_t)(a0_ + t) * C_ + ff] = w;
        }
    }
    if (LAST) {
        if (tid < TA_ * C_) {
            const int t = tid >> 7, ff = tid & 127;
            const int a = a0_ + t;
            const float y0 = ys[t][ff];
            const float yx = ys[t][C_ + ff], yy = ys[t][2 * C_ + ff], yz = ys[t][3 * C_ + ff];
            out[a * C_ + ff] = y0;                    // x0 [N,C,1]
            float* o1 = out + N_ * C_;                // x1 [N,C,3]
            o1[a * (C_ * 3) + ff * 3 + 0] = yx;
            o1[a * (C_ * 3) + ff * 3 + 1] = yy;
            o1[a * (C_ * 3) + ff * 3 + 2] = yz;
        }
        if (tid < TA_ * 8) {                          // atom head
            const int t = tid >> 3, o = tid & 7;
            float acc2 = predb[o];
            for (int c = 0; c < C_; ++c)
                acc2 = fmaf(predW[o * C_ + c], ys[t][c], acc2);
            out[N_ * C_ + N_ * C_ * 3 + (a0_ + t) * 8 + o] = acc2;
        }
    }
}

// ---------------------------------------------------------------------------
extern "C" void kernel_launch(void* const* d_in, const int* in_sizes, int n_in,
                              void* d_out, int out_size, void* d_ws, size_t ws_size,
                              hipStream_t stream)
{
    const float* r       = (const float*)d_in[0];
    const float* onehot  = (const float*)d_in[1];
    const float* embed_W = (const float*)d_in[2];
    const float* embed_b = (const float*)d_in[3];
    const float* Rw1     = (const float*)d_in[4];
    const float* Rb1     = (const float*)d_in[5];
    const float* Rw2     = (const float*)d_in[6];
    const float* Rb2     = (const float*)d_in[7];
    const float* si0_w0  = (const float*)d_in[8];
    const float* si0_b0  = (const float*)d_in[9];
    const float* si0_w1  = (const float*)d_in[10];
    const float* si1_w0  = (const float*)d_in[11];
    const float* si1_b0  = (const float*)d_in[12];
    const float* si1_w1  = (const float*)d_in[13];
    const float* si2_w0  = (const float*)d_in[14];
    const float* si2_b0  = (const float*)d_in[15];
    const float* si2_w1  = (const float*)d_in[16];
    const float* nl_b0   = (const float*)d_in[17];
    const float* nl_b1   = (const float*)d_in[18];
    const float* pred_W  = (const float*)d_in[19];
    const float* pred_b  = (const float*)d_in[20];
    (void)in_sizes; (void)n_in; (void)out_size; (void)ws_size;

    const float delta = DMAX_ / (float)(M_ - 1);

    // workspace (bytes): tab 3,145,728 | e 393,216 | xa/xb 786,432 each |
    // P = NSPLIT*N*11*C*4 = 12,976,128   -> total ~18.1MB (ws >= 24MB proven r8)
    char* wsb = (char*)d_ws;
    size_t off = 0;
    __half2* table = (__half2*)(wsb + off); off += (size_t)M_ * 12 * C_ * 4;
    float*   e     = (float*)(wsb + off);   off += (size_t)N_ * C_ * 4;
    uint2*   xa    = (uint2*)(wsb + off);   off += (size_t)N_ * C_ * 8;
    uint2*   xb    = (uint2*)(wsb + off);   off += (size_t)N_ * C_ * 8;
    float*   P     = (float*)(wsb + off);

    float* out = (float*)d_out;

    build_table_kernel<<<M_ / 4, 256, 0, stream>>>(Rw1, Rb1, Rw2, Rb2, table, delta);
    embed_kernel<<<(N_ * C_) / 256, 256, 0, stream>>>(onehot, embed_W, embed_b, e);

    // layer 0
    pair0_kernel<<<NSPLIT * N_, 256, 0, stream>>>(r, e, table, P);
    finish0_kernel<<<N_ / TA_, 512, 0, stream>>>(P, si0_w0, si0_b0, si0_w1,
                                                 nl_b0, xa);
    // layer 1
    pairF_kernel<<<NSPLIT * N_, 256, 0, stream>>>(r, xa, table, 2, P);
    finishF_kernel<true, false><<<N_ / TA_, 512, 0, stream>>>(
        P, si1_w0, si1_b0, si1_w1, nl_b1, xb, nullptr, nullptr, nullptr);

    // layer 2 (last)
    pairF_kernel<<<NSPLIT * N_, 256, 0, stream>>>(r, xb, table, 7, P);
    finishF_kernel<false, true><<<N_ / TA_, 512, 0, stream>>>(
        P, si2_w0, si2_b0, si2_w1, nullptr, nullptr, out, pred_W, pred_b);
}